// Round 1
// baseline (764.615 us; speedup 1.0000x reference)
//
#include <hip/hip_runtime.h>

#define S_LEN 2048
#define DHEAD 64
#define TQ 64
#define TK 64
#define NIT (S_LEN / TK)   // 32
#define BH 32
#define NWG ((S_LEN / TQ) * BH)   // 1024 blocks, all co-resident (256 CU x 4)
#define NXCD 8

typedef __attribute__((ext_vector_type(4))) short short4v;
typedef __attribute__((ext_vector_type(8))) short short8v;
typedef __attribute__((ext_vector_type(4))) float float4v;
typedef __attribute__((ext_vector_type(2))) int int2v;
typedef __attribute__((ext_vector_type(4))) int int4v;

// round-half-up fp32 -> bf16 (random data: tie bias negligible, no NaN in inputs)
__device__ __forceinline__ unsigned bfr(float x) {
    return __builtin_bit_cast(unsigned, x) + 0x8000u;
}
__device__ __forceinline__ int packbf(float a, float b) {
    return (int)((bfr(a) >> 16) | (bfr(b) & 0xFFFF0000u));
}

// One K-tile iteration: LDS-write(IT from regs) | barrier | prefetch(IT+1) |
// compute(IT) | barrier.  Prefetched K/V/mask regs get a full compute phase
// (~700 cyc) to cover HBM latency.  MCUR/MNEXT ping-pong (static indexing only).
#define FRA_BODY(IT, MCUR, MNEXT)                                              \
    {                                                                          \
        _Pragma("unroll")                                                      \
        for (int p = 0; p < 4; ++p) {                                          \
            int2v t; t.x = packbf(kv[p].x, kv[p].y);                           \
            t.y = packbf(kv[p].z, kv[p].w);                                    \
            *(short4v*)&Kt[(sr + 16 * p) * 72 + sc] =                          \
                __builtin_bit_cast(short4v, t);                                \
        }                                                                      \
        {                                                                      \
            int4v t0, t1;                                                      \
            t0.x = packbf(vv[0], vv[1]);   t0.y = packbf(vv[2], vv[3]);        \
            t0.z = packbf(vv[4], vv[5]);   t0.w = packbf(vv[6], vv[7]);        \
            t1.x = packbf(vv[8], vv[9]);   t1.y = packbf(vv[10], vv[11]);      \
            t1.z = packbf(vv[12], vv[13]); t1.w = packbf(vv[14], vv[15]);      \
            *(short8v*)&Vt[l * 72 + 16 * w]     = __builtin_bit_cast(short8v, t0); \
            *(short8v*)&Vt[l * 72 + 16 * w + 8] = __builtin_bit_cast(short8v, t1); \
        }                                                                      \
        __syncthreads();                                                       \
        {                                                                      \
            const int kpf = ((IT) + 1 < NIT) ? ((IT) + 1) * TK : 0;            \
            _Pragma("unroll")                                                  \
            for (int p = 0; p < 4; ++p)                                        \
                kv[p] = *(const float4v*)(kbase +                              \
                    (size_t)(kpf + sr + 16 * p) * DHEAD + sc);                 \
            _Pragma("unroll")                                                  \
            for (int i = 0; i < 16; ++i)                                       \
                vv[i] = vbase[(size_t)(kpf + 16 * w + i) * DHEAD + l];         \
            const float* mp = mrow + kpf + 4 * lg;                             \
            _Pragma("unroll")                                                  \
            for (int mt = 0; mt < 4; ++mt)                                     \
                MNEXT[mt] = __builtin_nontemporal_load(                        \
                    (const float4v*)(mp + 16 * mt));                           \
        }                                                                      \
        _Pragma("unroll")                                                      \
        for (int mt = 0; mt < 4; ++mt) {                                       \
            float4v c1 = {0.f, 0.f, 0.f, 0.f};                                 \
            _Pragma("unroll")                                                  \
            for (int s = 0; s < 4; ++s) {                                      \
                short4v a1 = *(const short4v*)&Kt[(16 * mt + ln) * 72 +        \
                                                  16 * s + 4 * lg];            \
                c1 = __builtin_amdgcn_mfma_f32_16x16x16bf16_1k(a1, qf[s], c1,  \
                                                               0, 0, 0);       \
            }                                                                  \
            float p0 = c1.x * MCUR[mt].x;                                      \
            float p1 = c1.y * MCUR[mt].y;                                      \
            float p2 = c1.z * MCUR[mt].z;                                      \
            float p3 = c1.w * MCUR[mt].w;                                      \
            rpart += fabsf(p0) + fabsf(p1) + fabsf(p2) + fabsf(p3);            \
            int2v t; t.x = packbf(p0, p1); t.y = packbf(p2, p3);               \
            short4v a2 = __builtin_bit_cast(short4v, t);                       \
            _Pragma("unroll")                                                  \
            for (int nt = 0; nt < 4; ++nt) {                                   \
                short4v b2 = *(const short4v*)&Vt[(16 * nt + ln) * 72 +        \
                                                  16 * mt + 4 * lg];           \
                oacc[nt] = __builtin_amdgcn_mfma_f32_16x16x16bf16_1k(          \
                    a2, b2, oacc[nt], 0, 0, 0);                                \
            }                                                                  \
        }                                                                      \
        __syncthreads();                                                       \
    }

__global__ __launch_bounds__(256, 4)
void fra_kernel(const float* __restrict__ qg, const float* __restrict__ kg,
                const float* __restrict__ vg, const float* __restrict__ mg,
                float* __restrict__ og) {
    const int tid = threadIdx.x;
    const int l  = tid & 63;      // lane
    const int w  = tid >> 6;      // wave 0..3
    const int lg = l >> 4;        // lane group 0..3
    const int ln = l & 15;        // lane-in-group

    // XCD-chunked bijective swizzle (NWG % 8 == 0): each XCD gets a contiguous
    // chunk of 128 blocks = 4 whole heads -> K/V working set 4 MB = its L2.
    const int wgid = ((int)blockIdx.x % NXCD) * (NWG / NXCD) + (int)blockIdx.x / NXCD;
    const int qt = wgid & 31;     // q-tile fast within chunk
    const int bh = wgid >> 5;
    const int q0 = qt * TQ;

    // K tile [k_local][d], bf16, stride 72; V transposed [d][k_local], bf16.
    // Mask no longer staged: direct global->fragment (zero reuse operand).
    __shared__ __align__(16) short Kt[64 * 72];
    __shared__ __align__(16) short Vt[64 * 72];

    const float* qbase = qg + (size_t)bh * S_LEN * DHEAD;
    const float* kbase = kg + (size_t)bh * S_LEN * DHEAD;
    const float* vbase = vg + (size_t)bh * S_LEN * DHEAD;
    // this thread's fixed mask row (q = q0 + 16w + ln)
    const float* mrow  = mg + (size_t)bh * S_LEN * S_LEN
                            + (size_t)(q0 + 16 * w + ln) * S_LEN;
    float*       obase = og + (size_t)bh * S_LEN * DHEAD;

    // ---- Q fragments (B operand of GEMM1): B1[d=16s+4lg+j][n=q=ln]
    const int qrow = q0 + 16 * w + ln;
    short4v qf[4];
    #pragma unroll
    for (int s = 0; s < 4; ++s) {
        float4v qv = *(const float4v*)(qbase + (size_t)qrow * DHEAD + 16 * s + 4 * lg);
        int2v t; t.x = packbf(qv.x, qv.y); t.y = packbf(qv.z, qv.w);
        qf[s] = __builtin_bit_cast(short4v, t);
    }

    float4v oacc[4] = {{0.f,0.f,0.f,0.f},{0.f,0.f,0.f,0.f},
                       {0.f,0.f,0.f,0.f},{0.f,0.f,0.f,0.f}};
    float rpart = 0.f;

    const int sr = tid >> 4;         // staging row 0..15 (+16p)
    const int sc = (tid & 15) * 4;   // staging col (float4)

    // ---- staging registers (single set for K/V: written to LDS before reload;
    //      ping-pong pair for mask: in flight during its consumer phase)
    float4v kv[4];
    float   vv[16];
    float4v ma[4], mb[4];

    // ---- prologue: issue tile-0 loads
    #pragma unroll
    for (int p = 0; p < 4; ++p)
        kv[p] = *(const float4v*)(kbase + (size_t)(sr + 16 * p) * DHEAD + sc);
    #pragma unroll
    for (int i = 0; i < 16; ++i)
        vv[i] = vbase[(size_t)(16 * w + i) * DHEAD + l];
    #pragma unroll
    for (int mt = 0; mt < 4; ++mt)
        ma[mt] = __builtin_nontemporal_load(
            (const float4v*)(mrow + 16 * mt + 4 * lg));

    // ---- main loop, manual 2x unroll for the mask reg ping-pong (NIT even)
    for (int itp = 0; itp < NIT; itp += 2) {
        FRA_BODY(itp,     ma, mb)
        FRA_BODY(itp + 1, mb, ma)
    }

    // ---- r: lane holds partial for q-col (ln); sum across the 4 lane groups
    float r = rpart;
    r += __shfl_xor(r, 16);
    r += __shfl_xor(r, 32);

    // ---- epilogue: O rows are q = qw + 4lg + reg (C layout), cols d = 16nt + ln
    #pragma unroll
    for (int reg = 0; reg < 4; ++reg) {
        float rq  = __shfl(r, 4 * lg + reg);
        float inv = 1.0f / fmaxf(rq, 1.0f);
        const int orow = q0 + 16 * w + 4 * lg + reg;
        #pragma unroll
        for (int nt = 0; nt < 4; ++nt) {
            __builtin_nontemporal_store(oacc[nt][reg] * inv,
                &obase[(size_t)orow * DHEAD + 16 * nt + ln]);
        }
    }
}

extern "C" void kernel_launch(void* const* d_in, const int* in_sizes, int n_in,
                              void* d_out, int out_size, void* d_ws, size_t ws_size,
                              hipStream_t stream) {
    const float* q = (const float*)d_in[0];
    const float* k = (const float*)d_in[1];
    const float* v = (const float*)d_in[2];
    const float* m = (const float*)d_in[3];
    float* o = (float*)d_out;
    (void)in_sizes; (void)n_in; (void)out_size; (void)d_ws; (void)ws_size;
    fra_kernel<<<dim3(NWG), dim3(256, 1, 1), 0, stream>>>(q, k, v, m, o);
}